// Round 7
// baseline (378.359 us; speedup 1.0000x reference)
//
#include <hip/hip_runtime.h>
#include <math.h>

#define Lq 256
#define Dm 300
#define Sq 16
#define Kc 16
#define Eq 2048
#define D4 75   // Dm/4 float4s per row

// ---------------- Kernel A: 6 fused row matmuls (utt @ {Wb0,Wb1,Wself,Wq,Wk,Wv}) ----
__global__ __launch_bounds__(256) void mm6_kernel(
    const float* __restrict__ utt,
    const float* __restrict__ Wb,
    const float* __restrict__ Wself,
    const float* __restrict__ brgcn,
    const float* __restrict__ Wq,
    const float* __restrict__ Wk,
    const float* __restrict__ Wv,
    float* __restrict__ P0, float* __restrict__ P1,
    float* __restrict__ Hrg, float* __restrict__ Q,
    float* __restrict__ Km, float* __restrict__ Vm)
{
    const int m = blockIdx.y;
    const float* W; float* Y; const float* bias = nullptr;
    switch (m) {
      case 0: W = Wb;          Y = P0; break;
      case 1: W = Wb + 90000;  Y = P1; break;
      case 2: W = Wself;       Y = Hrg; bias = brgcn; break;
      case 3: W = Wq;          Y = Q; break;
      case 4: W = Wk;          Y = Km; break;
      default: W = Wv;         Y = Vm; break;
    }
    const int row0 = blockIdx.x * 4;
    __shared__ float xs[4][Dm];
    for (int i = threadIdx.x; i < 4*Dm; i += 256)
        xs[i/Dm][i%Dm] = utt[(row0 + i/Dm)*Dm + (i%Dm)];
    __syncthreads();
    for (int c = threadIdx.x; c < Dm; c += 256) {
        float a0=0.f,a1=0.f,a2=0.f,a3=0.f;
        #pragma unroll 10
        for (int d = 0; d < Dm; ++d) {
            float wv = W[d*Dm + c];
            a0 += xs[0][d]*wv; a1 += xs[1][d]*wv;
            a2 += xs[2][d]*wv; a3 += xs[3][d]*wv;
        }
        float b = bias ? bias[c] : 0.f;
        Y[(row0+0)*Dm+c] = a0+b;
        Y[(row0+1)*Dm+c] = a1+b;
        Y[(row0+2)*Dm+c] = a2+b;
        Y[(row0+3)*Dm+c] = a3+b;
    }
}

// ---------------- Kernel B: RGCN edge accumulation -------------------------------
__global__ __launch_bounds__(64) void rgcn_edge_kernel(
    const int* __restrict__ src, const int* __restrict__ dst, const int* __restrict__ et,
    const float* __restrict__ comp, const float* __restrict__ P0,
    const float* __restrict__ P1, float* __restrict__ Hrg)
{
    int e = blockIdx.x;
    int s = src[e], d = dst[e], r = et[e];
    float c0 = comp[r*2], c1 = comp[r*2+1];
    for (int i = threadIdx.x; i < Dm; i += 64) {
        float msg = c0*P0[s*Dm+i] + c1*P1[s*Dm+i];
        atomicAdd(&Hrg[d*Dm+i], msg);
    }
}

// ------- Kernel C: fused window attention + @Wo, grid (Lq, 2) --------------------
// Wave 0 computes the 3-wide attention context for row l into LDS; then 150
// threads compute the half's columns of ctx @ Wo.
__global__ __launch_bounds__(256) void attn_out_kernel(
    const float* __restrict__ Q, const float* __restrict__ Kmat,
    const float* __restrict__ Vmat, const float* __restrict__ W,
    float* __restrict__ Y)
{
    const int l = blockIdx.x, half = blockIdx.y;
    const int tid = threadIdx.x, lane = tid & 63, wave = tid >> 6;
    __shared__ float xs[Dm];

    if (wave == 0) {
        const int w0 = l > 0 ? l-1 : 0;
        const int w1 = l;
        const int w2 = l < Lq-1 ? l+1 : Lq-1;
        const int win[3] = {w0, w1, w2};
        float sc[2][3];
        #pragma unroll
        for (int h = 0; h < 2; ++h) {
          #pragma unroll
          for (int w = 0; w < 3; ++w) {
            float acc = 0.f;
            const float* qp = Q + l*Dm + h*150;
            const float* kp = Kmat + win[w]*Dm + h*150;
            for (int d = lane; d < 150; d += 64) acc += qp[d]*kp[d];
            #pragma unroll
            for (int off = 32; off; off >>= 1) acc += __shfl_xor(acc, off);
            sc[h][w] = acc * 0.081649658092772603f;   // 1/sqrt(150)
          }
        }
        float attn[2][3];
        #pragma unroll
        for (int h = 0; h < 2; ++h) {
          float m = fmaxf(sc[h][0], fmaxf(sc[h][1], sc[h][2]));
          float e0 = expf(sc[h][0]-m), e1 = expf(sc[h][1]-m), e2 = expf(sc[h][2]-m);
          float iz = 1.f/(e0+e1+e2);
          attn[h][0]=e0*iz; attn[h][1]=e1*iz; attn[h][2]=e2*iz;
        }
        for (int d = lane; d < Dm; d += 64) {
          int h = d / 150;
          xs[d] = attn[h][0]*Vmat[w0*Dm+d] + attn[h][1]*Vmat[w1*Dm+d]
                + attn[h][2]*Vmat[w2*Dm+d];
        }
    }
    __syncthreads();

    if (tid < 150) {
        const int c = half*150 + tid;
        float acc = 0.f;
        #pragma unroll 10
        for (int d = 0; d < Dm; ++d)
            acc += xs[d] * W[d*Dm + c];
        Y[l*Dm + c] = acc;
    }
}

// ---------------- Kernel D: concept attention, register row cache ----------------
// One block per (g,l,s) cell, 8 blocks/CU (LDS ~9 KB). 16 lane-groups gather 16
// table rows into REGISTERS (5 float4/lane); pass 2 is a register scatter-reduce
// via __shfl_xor across groups + a 4x75-float4 LDS partial buffer. unorm computed
// in-block from s_u. Fused score epilogue.
__global__ __launch_bounds__(256) void concept_kernel(
    const int* __restrict__ src_ids,
    const int* __restrict__ dst_ids,
    const float* __restrict__ cw,
    const float* __restrict__ csen,
    const float* __restrict__ table,
    const float* __restrict__ relatt,
    const float* __restrict__ rvecs,
    float* __restrict__ src2,
    float* __restrict__ score)
{
    int cell = blockIdx.x;            // (g*L + l)*S + s
    int g = cell / (Lq*Sq);
    int l = (cell / Sq) % Lq;
    int s = cell % Sq;
    int tid = threadIdx.x, lane = tid & 63, wave = tid >> 6;

    int sid = src_ids[cell];
    if (sid < 0) {                    // block-uniform early exit (~10% of cells)
        if (tid == 0) score[l*48 + g*Sq + s] = -1e30f;
        return;
    }

    __shared__ float4 s_u[D4+1], s_src[D4+1], s_r[D4+1];
    __shared__ float4 s_part[4][D4+1];
    __shared__ float  s_du[Kc], s_dw[Kc], s_dn[Kc], s_beta[Kc];
    __shared__ float  s_sc[16];
    __shared__ int    s_dst[Kc];

    const int base = cell * Kc;
    if (tid < D4)              s_u[tid]        = ((const float4*)(relatt + l*Dm))[tid];
    else if (tid < 2*D4)       s_src[tid-D4]   = ((const float4*)(table + (size_t)sid*Dm))[tid-D4];
    else if (tid < 3*D4)       s_r[tid-2*D4]   = ((const float4*)(rvecs + g*Dm))[tid-2*D4];
    else if (tid < 3*D4+Kc)    s_dst[tid-3*D4] = dst_ids[base + tid - 3*D4];
    __syncthreads();

    // ---- per-wave redundant ||u||^2 (no extra sync) ----
    float un = 0.f;
    for (int idx = lane; idx < D4; idx += 64) {
        float4 u = s_u[idx];
        un += u.x*u.x + u.y*u.y + u.z*u.z + u.w*u.w;
    }
    #pragma unroll
    for (int off = 32; off; off >>= 1) un += __shfl_xor(un, off);
    float unorm_l = sqrtf(un);

    // ---- pass 1: 16 concurrent row gathers into registers + 3 dots ----
    int grp = lane >> 4, gl = lane & 15;
    int k = wave*4 + grp;
    int did = s_dst[k];
    float4 v[5];
    float du = 0.f, dw = 0.f, dn = 0.f;
    #pragma unroll
    for (int j = 0; j < 5; ++j) v[j] = make_float4(0.f,0.f,0.f,0.f);
    if (did >= 0) {
        const float4* rp = (const float4*)(table + (size_t)did*Dm);
        #pragma unroll
        for (int j = 0; j < 5; ++j) {
            int idx = gl + 16*j;
            if (idx < D4) {
                float4 t = rp[idx];
                v[j] = t;
                float4 u = s_u[idx], sr = s_src[idx], rr = s_r[idx];
                du += t.x*u.x + t.y*u.y + t.z*u.z + t.w*u.w;
                dw += t.x*sr.x*rr.x + t.y*sr.y*rr.y + t.z*sr.z*rr.z + t.w*sr.w*rr.w;
                dn += t.x*t.x + t.y*t.y + t.z*t.z + t.w*t.w;
            }
        }
    }
    #pragma unroll
    for (int off = 8; off; off >>= 1) {
        du += __shfl_down(du, off, 16);
        dw += __shfl_down(dw, off, 16);
        dn += __shfl_down(dn, off, 16);
    }
    if (gl == 0) { s_du[k] = du; s_dw[k] = dw; s_dn[k] = dn; }
    __syncthreads();

    // ---- softmax chain: 16 parallel lanes, width-16 butterflies ----
    if (wave == 0 && lane < Kc) {
        int kk = lane;
        int msk = (s_dst[kk] >= 0) ? 1 : 0;
        float pre = -1e30f;
        if (msk) {
            float cosv = fabsf(s_du[kk]) / (unorm_l*sqrtf(s_dn[kk]) + 1e-8f);
            pre = 0.5f*cw[base+kk]*cosv + 0.5f*fabsf(csen[base+kk]);
        }
        float mx = pre;
        #pragma unroll
        for (int off = 8; off; off >>= 1) mx = fmaxf(mx, __shfl_xor(mx, off, 16));
        float e1 = msk ? expf(pre - mx) : 0.f;
        float Z = e1;
        #pragma unroll
        for (int off = 8; off; off >>= 1) Z += __shfl_xor(Z, off, 16);
        float beta = 0.f;
        if (Z > 0.f) {
            float a1 = e1 / Z;
            float sv = msk ? a1 * s_dw[kk] : -1e30f;
            float mx2 = sv;
            #pragma unroll
            for (int off = 8; off; off >>= 1) mx2 = fmaxf(mx2, __shfl_xor(mx2, off, 16));
            float e2 = msk ? expf(sv - mx2) : 0.f;
            float Z2 = e2;
            #pragma unroll
            for (int off = 8; off; off >>= 1) Z2 += __shfl_xor(Z2, off, 16);
            beta = a1 * (e2 / Z2);
        }
        s_beta[kk] = beta;
    }
    __syncthreads();

    // ---- pass 2: register scatter-reduce (beta-weighted rows) ----
    float b = s_beta[k];              // this lane-group's k (invalid k => beta 0, v 0)
    #pragma unroll
    for (int j = 0; j < 5; ++j) {
        v[j].x *= b; v[j].y *= b; v[j].z *= b; v[j].w *= b;
        // sum across the 4 groups of this wave (lanes differing in bits 4,5)
        v[j].x += __shfl_xor(v[j].x, 16); v[j].x += __shfl_xor(v[j].x, 32);
        v[j].y += __shfl_xor(v[j].y, 16); v[j].y += __shfl_xor(v[j].y, 32);
        v[j].z += __shfl_xor(v[j].z, 16); v[j].z += __shfl_xor(v[j].z, 32);
        v[j].w += __shfl_xor(v[j].w, 16); v[j].w += __shfl_xor(v[j].w, 32);
    }
    if (grp == 0) {
        #pragma unroll
        for (int j = 0; j < 5; ++j) {
            int idx = gl + 16*j;
            if (idx < D4) s_part[wave][idx] = v[j];
        }
    }
    __syncthreads();

    // ---- final: combine 4 wave partials, write src2, fused score dot ----
    float dot = 0.f;
    if (tid < D4) {
        float4 p0 = s_part[0][tid], p1 = s_part[1][tid];
        float4 p2 = s_part[2][tid], p3 = s_part[3][tid];
        float4 acc;
        acc.x = p0.x+p1.x+p2.x+p3.x;
        acc.y = p0.y+p1.y+p2.y+p3.y;
        acc.z = p0.z+p1.z+p2.z+p3.z;
        acc.w = p0.w+p1.w+p2.w+p3.w;
        float4 sv = s_src[tid], rv = s_r[tid];
        float4 o;
        o.x = sv.x + rv.x*acc.x;
        o.y = sv.y + rv.y*acc.y;
        o.z = sv.z + rv.z*acc.z;
        o.w = sv.w + rv.w*acc.w;
        ((float4*)(src2 + (size_t)cell*Dm))[tid] = o;
        float4 u = s_u[tid];
        dot = o.x*u.x + o.y*u.y + o.z*u.z + o.w*u.w;
    }
    if (wave == 1 && lane < 16) s_sc[lane] = dot;   // tids 64..74 carry, 75..79 zero
    __syncthreads();
    if (wave == 0) {
        float vv = dot + (lane < 16 ? s_sc[lane] : 0.f);
        #pragma unroll
        for (int off = 32; off; off >>= 1) vv += __shfl_down(vv, off);
        if (lane == 0)
            score[l*48 + g*Sq + s] = vv;
    }
}

// ---------------- Kernel F1: fused MLP layer-1 (K-split x9) + inline sym ---------
__global__ __launch_bounds__(256) void fuse1_kernel(
    const float* __restrict__ Hrg, const float* __restrict__ relatt,
    const float* __restrict__ score, const float* __restrict__ src2,
    const float* __restrict__ Wf, float* __restrict__ part)
{
    int l = blockIdx.x, j = blockIdx.y, tid = threadIdx.x;
    const int k0 = j * 100;
    const int seg = j / 3;            // 0:Hrg 1:rel 2:sym
    const int koff = (j % 3) * 100;
    __shared__ float s_f[100];
    __shared__ float s_att[48];
    if (seg == 2 && tid < 64) {
        float sv = (tid < 48) ? score[l*48+tid] : -1e30f;
        float mx = sv;
        #pragma unroll
        for (int off = 32; off; off >>= 1) mx = fmaxf(mx, __shfl_xor(mx, off));
        float e = (sv > -1e29f) ? expf(sv-mx) : 0.f;
        float Z = e;
        #pragma unroll
        for (int off = 32; off; off >>= 1) Z += __shfl_xor(Z, off);
        float iZ = (Z > 0.f) ? 1.f/Z : 0.f;
        if (tid < 48) s_att[tid] = e*iZ;
    }
    __syncthreads();
    if (tid < 100) {
        if (seg == 0)      s_f[tid] = Hrg[l*Dm + koff + tid];
        else if (seg == 1) s_f[tid] = relatt[l*Dm + koff + tid];
        else {
            float acc = 0.f;
            for (int n = 0; n < 48; ++n) {
                float a = s_att[n];
                if (a != 0.f) {
                    int gg = n >> 4, ss = n & 15;
                    acc += a * src2[(size_t)((gg*Lq + l)*Sq + ss)*Dm + koff + tid];
                }
            }
            s_f[tid] = acc;
        }
    }
    __syncthreads();
    for (int c = tid; c < Dm; c += 256) {
        float acc = 0.f;
        #pragma unroll 10
        for (int i = 0; i < 100; ++i)
            acc += s_f[i] * Wf[(k0 + i)*Dm + c];
        part[(size_t)j*Lq*Dm + l*Dm + c] = acc;
    }
}

// ---------------- Kernel F2: combine + relu + out matvec + log_softmax -----------
__global__ __launch_bounds__(256) void fuse2_kernel(
    const float* __restrict__ part, const float* __restrict__ bf,
    const float* __restrict__ Wout, const float* __restrict__ bout,
    float* __restrict__ out)
{
    int l = blockIdx.x, tid = threadIdx.x;
    __shared__ float s_h1[Dm];
    __shared__ float s_logit[7];
    for (int c = tid; c < Dm; c += 256) {
        float acc = bf[c];
        #pragma unroll
        for (int j = 0; j < 9; ++j)
            acc += part[(size_t)j*Lq*Dm + l*Dm + c];
        s_h1[c] = fmaxf(acc, 0.f);
    }
    __syncthreads();
    if (tid < 64) {
        for (int c = 0; c < 7; ++c) {
            float acc = 0.f;
            for (int i = tid; i < Dm; i += 64) acc += s_h1[i]*Wout[i*7+c];
            for (int off = 32; off > 0; off >>= 1) acc += __shfl_down(acc, off);
            if (tid == 0) s_logit[c] = acc + bout[c];
        }
    }
    __syncthreads();
    if (tid == 0) {
        float mx = s_logit[0];
        for (int c = 1; c < 7; ++c) mx = fmaxf(mx, s_logit[c]);
        float Z = 0.f;
        for (int c = 0; c < 7; ++c) Z += expf(s_logit[c]-mx);
        float lz = logf(Z) + mx;
        for (int c = 0; c < 7; ++c) out[l*7+c] = s_logit[c] - lz;
    }
}

extern "C" void kernel_launch(void* const* d_in, const int* in_sizes, int n_in,
                              void* d_out, int out_size, void* d_ws, size_t ws_size,
                              hipStream_t stream)
{
    const float* utt   = (const float*)d_in[0];
    const int* str_src = (const int*)d_in[1];
    const int* str_dst = (const int*)d_in[2];
    const int* str_et  = (const int*)d_in[3];
    const int* csrc    = (const int*)d_in[4];
    const int* cdst    = (const int*)d_in[5];
    const float* cw    = (const float*)d_in[6];
    const float* csen  = (const float*)d_in[7];
    const float* table = (const float*)d_in[8];
    const float* Wb    = (const float*)d_in[9];
    const float* comp  = (const float*)d_in[10];
    const float* Wself = (const float*)d_in[11];
    const float* brg   = (const float*)d_in[12];
    const float* Wq    = (const float*)d_in[13];
    const float* Wk    = (const float*)d_in[14];
    const float* Wv    = (const float*)d_in[15];
    const float* Wo    = (const float*)d_in[16];
    const float* rvec  = (const float*)d_in[17];
    const float* Wf    = (const float*)d_in[18];
    const float* bf    = (const float*)d_in[19];
    const float* Wout  = (const float*)d_in[20];
    const float* bout  = (const float*)d_in[21];

    float* ws   = (float*)d_ws;
    float* P0   = ws;               // 76800
    float* P1   = P0 + 76800;
    float* Q    = P1 + 76800;
    float* Km   = Q  + 76800;
    float* Vm   = Km + 76800;
    float* Hrg  = Vm + 76800;
    float* rel  = Hrg + 76800;
    float* score= rel + 76800;      // 12288 (256*48)
    float* part = score + 12288;    // 691200 (9*256*300)
    float* src2 = part + 691200;    // 3,686,400

    mm6_kernel<<<dim3(64,6), 256, 0, stream>>>(utt, Wb, Wself, brg, Wq, Wk, Wv,
                                               P0, P1, Hrg, Q, Km, Vm);
    rgcn_edge_kernel<<<Eq, 64, 0, stream>>>(str_src, str_dst, str_et, comp, P0, P1, Hrg);
    attn_out_kernel<<<dim3(Lq,2), 256, 0, stream>>>(Q, Km, Vm, Wo, rel);
    concept_kernel<<<3*Lq*Sq, 256, 0, stream>>>(csrc, cdst, cw, csen, table, rel,
                                                rvec, src2, score);
    fuse1_kernel<<<dim3(Lq,9), 256, 0, stream>>>(Hrg, rel, score, src2, Wf, part);
    fuse2_kernel<<<Lq, 256, 0, stream>>>(part, bf, Wout, bout, (float*)d_out);
}

// Round 8
// 356.008 us; speedup vs baseline: 1.0628x; 1.0628x over previous
//
#include <hip/hip_runtime.h>
#include <math.h>

#define Lq 256
#define Dm 300
#define Sq 16
#define Kc 16
#define Eq 2048
#define D4 75   // Dm/4 float4s per row

// ---------------- Kernel A: 6 fused row matmuls (utt @ {Wb0,Wb1,Wself,Wq,Wk,Wv}) ----
__global__ __launch_bounds__(256) void mm6_kernel(
    const float* __restrict__ utt,
    const float* __restrict__ Wb,
    const float* __restrict__ Wself,
    const float* __restrict__ brgcn,
    const float* __restrict__ Wq,
    const float* __restrict__ Wk,
    const float* __restrict__ Wv,
    float* __restrict__ P0, float* __restrict__ P1,
    float* __restrict__ Hrg, float* __restrict__ Q,
    float* __restrict__ Km, float* __restrict__ Vm)
{
    const int m = blockIdx.y;
    const float* W; float* Y; const float* bias = nullptr;
    switch (m) {
      case 0: W = Wb;          Y = P0; break;
      case 1: W = Wb + 90000;  Y = P1; break;
      case 2: W = Wself;       Y = Hrg; bias = brgcn; break;
      case 3: W = Wq;          Y = Q; break;
      case 4: W = Wk;          Y = Km; break;
      default: W = Wv;         Y = Vm; break;
    }
    const int row0 = blockIdx.x * 4;
    __shared__ float xs[4][Dm];
    for (int i = threadIdx.x; i < 4*Dm; i += 256)
        xs[i/Dm][i%Dm] = utt[(row0 + i/Dm)*Dm + (i%Dm)];
    __syncthreads();
    for (int c = threadIdx.x; c < Dm; c += 256) {
        float a0=0.f,a1=0.f,a2=0.f,a3=0.f;
        #pragma unroll 10
        for (int d = 0; d < Dm; ++d) {
            float wv = W[d*Dm + c];
            a0 += xs[0][d]*wv; a1 += xs[1][d]*wv;
            a2 += xs[2][d]*wv; a3 += xs[3][d]*wv;
        }
        float b = bias ? bias[c] : 0.f;
        Y[(row0+0)*Dm+c] = a0+b;
        Y[(row0+1)*Dm+c] = a1+b;
        Y[(row0+2)*Dm+c] = a2+b;
        Y[(row0+3)*Dm+c] = a3+b;
    }
}

// ---------------- Kernel B: RGCN edge accumulation -------------------------------
__global__ __launch_bounds__(64) void rgcn_edge_kernel(
    const int* __restrict__ src, const int* __restrict__ dst, const int* __restrict__ et,
    const float* __restrict__ comp, const float* __restrict__ P0,
    const float* __restrict__ P1, float* __restrict__ Hrg)
{
    int e = blockIdx.x;
    int s = src[e], d = dst[e], r = et[e];
    float c0 = comp[r*2], c1 = comp[r*2+1];
    for (int i = threadIdx.x; i < Dm; i += 64) {
        float msg = c0*P0[s*Dm+i] + c1*P1[s*Dm+i];
        atomicAdd(&Hrg[d*Dm+i], msg);
    }
}

// ------- Kernel C: fused window attention + @Wo, grid (Lq, 2) --------------------
__global__ __launch_bounds__(256) void attn_out_kernel(
    const float* __restrict__ Q, const float* __restrict__ Kmat,
    const float* __restrict__ Vmat, const float* __restrict__ W,
    float* __restrict__ Y)
{
    const int l = blockIdx.x, half = blockIdx.y;
    const int tid = threadIdx.x, lane = tid & 63, wave = tid >> 6;
    __shared__ float xs[Dm];

    if (wave == 0) {
        const int w0 = l > 0 ? l-1 : 0;
        const int w1 = l;
        const int w2 = l < Lq-1 ? l+1 : Lq-1;
        const int win[3] = {w0, w1, w2};
        float sc[2][3];
        #pragma unroll
        for (int h = 0; h < 2; ++h) {
          #pragma unroll
          for (int w = 0; w < 3; ++w) {
            float acc = 0.f;
            const float* qp = Q + l*Dm + h*150;
            const float* kp = Kmat + win[w]*Dm + h*150;
            for (int d = lane; d < 150; d += 64) acc += qp[d]*kp[d];
            #pragma unroll
            for (int off = 32; off; off >>= 1) acc += __shfl_xor(acc, off);
            sc[h][w] = acc * 0.081649658092772603f;   // 1/sqrt(150)
          }
        }
        float attn[2][3];
        #pragma unroll
        for (int h = 0; h < 2; ++h) {
          float m = fmaxf(sc[h][0], fmaxf(sc[h][1], sc[h][2]));
          float e0 = expf(sc[h][0]-m), e1 = expf(sc[h][1]-m), e2 = expf(sc[h][2]-m);
          float iz = 1.f/(e0+e1+e2);
          attn[h][0]=e0*iz; attn[h][1]=e1*iz; attn[h][2]=e2*iz;
        }
        for (int d = lane; d < Dm; d += 64) {
          int h = d / 150;
          xs[d] = attn[h][0]*Vmat[w0*Dm+d] + attn[h][1]*Vmat[w1*Dm+d]
                + attn[h][2]*Vmat[w2*Dm+d];
        }
    }
    __syncthreads();

    if (tid < 150) {
        const int c = half*150 + tid;
        float acc = 0.f;
        #pragma unroll 10
        for (int d = 0; d < Dm; ++d)
            acc += xs[d] * W[d*Dm + c];
        Y[l*Dm + c] = acc;
    }
}

// ---------------- Kernel D: concept attention (LDS row cache, R5 structure) ------
// One block per (g,l,s) cell. 16 lane-groups gather 16 table rows concurrently
// (float4), caching rows in LDS; pass 2 reads LDS only. In-block ||u||; fused
// score epilogue. Unconditional gathers (invalid ids fall back to row 0 — L3-hot).
__global__ __launch_bounds__(256) void concept_kernel(
    const int* __restrict__ src_ids,
    const int* __restrict__ dst_ids,
    const float* __restrict__ cw,
    const float* __restrict__ csen,
    const float* __restrict__ table,
    const float* __restrict__ relatt,
    const float* __restrict__ rvecs,
    float* __restrict__ src2,
    float* __restrict__ score)
{
    int cell = blockIdx.x;            // (g*L + l)*S + s
    int g = cell / (Lq*Sq);
    int l = (cell / Sq) % Lq;
    int s = cell % Sq;
    int tid = threadIdx.x, lane = tid & 63, wave = tid >> 6;

    __shared__ float4 s_rows[Kc][D4+1];
    __shared__ float4 s_u[D4+1], s_src[D4+1], s_r[D4+1];
    __shared__ float  s_du[Kc], s_dw[Kc], s_dn[Kc], s_beta[Kc];
    __shared__ float  s_part[16];
    __shared__ int    s_dst[Kc];

    const int base = cell * Kc;
    int sid = src_ids[cell];
    int srow = sid >= 0 ? sid : 0;
    if (tid < D4)              s_u[tid]        = ((const float4*)(relatt + l*Dm))[tid];
    else if (tid < 2*D4)       s_src[tid-D4]   = ((const float4*)(table + (size_t)srow*Dm))[tid-D4];
    else if (tid < 3*D4)       s_r[tid-2*D4]   = ((const float4*)(rvecs + g*Dm))[tid-2*D4];
    else if (tid < 3*D4+Kc)    s_dst[tid-3*D4] = dst_ids[base + tid - 3*D4];
    __syncthreads();

    // ---- per-wave redundant ||u||^2 (no extra sync) ----
    float un = 0.f;
    for (int idx = lane; idx < D4; idx += 64) {
        float4 u = s_u[idx];
        un += u.x*u.x + u.y*u.y + u.z*u.z + u.w*u.w;
    }
    #pragma unroll
    for (int off = 32; off; off >>= 1) un += __shfl_xor(un, off);
    float unorm_l = sqrtf(un);

    // ---- pass 1: 16 concurrent row gathers + 3 dots per row, rows -> LDS ----
    int grp = lane >> 4, gl = lane & 15;
    int k = wave*4 + grp;
    int did = s_dst[k];
    const float4* rp = (const float4*)(table + (size_t)(did >= 0 ? did : 0)*Dm);
    float du = 0.f, dw = 0.f, dn = 0.f;
    #pragma unroll
    for (int j = 0; j < 5; ++j) {
        int idx = gl + 16*j;
        if (idx < D4) {
            float4 v = rp[idx];
            s_rows[k][idx] = v;
            float4 u = s_u[idx], sr = s_src[idx], rr = s_r[idx];
            du += v.x*u.x + v.y*u.y + v.z*u.z + v.w*u.w;
            dw += v.x*sr.x*rr.x + v.y*sr.y*rr.y + v.z*sr.z*rr.z + v.w*sr.w*rr.w;
            dn += v.x*v.x + v.y*v.y + v.z*v.z + v.w*v.w;
        }
    }
    #pragma unroll
    for (int off = 8; off; off >>= 1) {
        du += __shfl_down(du, off, 16);
        dw += __shfl_down(dw, off, 16);
        dn += __shfl_down(dn, off, 16);
    }
    if (gl == 0) { s_du[k] = du; s_dw[k] = dw; s_dn[k] = dn; }
    __syncthreads();

    // ---- softmax chain: 16 parallel lanes, width-16 butterflies ----
    if (wave == 0 && lane < Kc) {
        int kk = lane;
        int msk = (s_dst[kk] >= 0) ? 1 : 0;
        float pre = -1e30f;
        if (msk) {
            float cosv = fabsf(s_du[kk]) / (unorm_l*sqrtf(s_dn[kk]) + 1e-8f);
            pre = 0.5f*cw[base+kk]*cosv + 0.5f*fabsf(csen[base+kk]);
        }
        float mx = pre;
        #pragma unroll
        for (int off = 8; off; off >>= 1) mx = fmaxf(mx, __shfl_xor(mx, off, 16));
        float e1 = msk ? expf(pre - mx) : 0.f;
        float Z = e1;
        #pragma unroll
        for (int off = 8; off; off >>= 1) Z += __shfl_xor(Z, off, 16);
        float beta = 0.f;
        if (Z > 0.f) {
            float a1 = e1 / Z;
            float sv = msk ? a1 * s_dw[kk] : -1e30f;
            float mx2 = sv;
            #pragma unroll
            for (int off = 8; off; off >>= 1) mx2 = fmaxf(mx2, __shfl_xor(mx2, off, 16));
            float e2 = msk ? expf(sv - mx2) : 0.f;
            float Z2 = e2;
            #pragma unroll
            for (int off = 8; off; off >>= 1) Z2 += __shfl_xor(Z2, off, 16);
            beta = a1 * (e2 / Z2);
        }
        s_beta[kk] = beta;
    }
    __syncthreads();

    // ---- pass 2: weighted sum from LDS-cached rows + fused score dot ----
    float dot = 0.f;
    if (tid < D4) {
        float4 acc = make_float4(0.f, 0.f, 0.f, 0.f);
        #pragma unroll
        for (int kk = 0; kk < Kc; ++kk) {
            float b = s_beta[kk];
            float4 v = s_rows[kk][tid];
            acc.x += b*v.x; acc.y += b*v.y; acc.z += b*v.z; acc.w += b*v.w;
        }
        float4 sv = s_src[tid], rv = s_r[tid];
        float4 o;
        o.x = sv.x + rv.x*acc.x;
        o.y = sv.y + rv.y*acc.y;
        o.z = sv.z + rv.z*acc.z;
        o.w = sv.w + rv.w*acc.w;
        ((float4*)(src2 + (size_t)cell*Dm))[tid] = o;
        float4 u = s_u[tid];
        dot = o.x*u.x + o.y*u.y + o.z*u.z + o.w*u.w;
    }
    if (wave == 1 && lane < 16) s_part[lane] = dot;   // tids 64..74 carry, 75..79 zero
    __syncthreads();
    if (wave == 0) {
        float v = dot + (lane < 16 ? s_part[lane] : 0.f);
        #pragma unroll
        for (int off = 32; off; off >>= 1) v += __shfl_down(v, off);
        if (lane == 0)
            score[l*48 + g*Sq + s] = (sid >= 0) ? v : -1e30f;
    }
}

// ---------------- Kernel F1: fused MLP layer-1 (K-split x9) + inline sym ---------
__global__ __launch_bounds__(256) void fuse1_kernel(
    const float* __restrict__ Hrg, const float* __restrict__ relatt,
    const float* __restrict__ score, const float* __restrict__ src2,
    const float* __restrict__ Wf, float* __restrict__ part)
{
    int l = blockIdx.x, j = blockIdx.y, tid = threadIdx.x;
    const int k0 = j * 100;
    const int seg = j / 3;            // 0:Hrg 1:rel 2:sym
    const int koff = (j % 3) * 100;
    __shared__ float s_f[100];
    __shared__ float s_att[48];
    if (seg == 2 && tid < 64) {
        float sv = (tid < 48) ? score[l*48+tid] : -1e30f;
        float mx = sv;
        #pragma unroll
        for (int off = 32; off; off >>= 1) mx = fmaxf(mx, __shfl_xor(mx, off));
        float e = (sv > -1e29f) ? expf(sv-mx) : 0.f;
        float Z = e;
        #pragma unroll
        for (int off = 32; off; off >>= 1) Z += __shfl_xor(Z, off);
        float iZ = (Z > 0.f) ? 1.f/Z : 0.f;
        if (tid < 48) s_att[tid] = e*iZ;
    }
    __syncthreads();
    if (tid < 100) {
        if (seg == 0)      s_f[tid] = Hrg[l*Dm + koff + tid];
        else if (seg == 1) s_f[tid] = relatt[l*Dm + koff + tid];
        else {
            float acc = 0.f;
            for (int n = 0; n < 48; ++n) {
                float a = s_att[n];
                if (a != 0.f) {
                    int gg = n >> 4, ss = n & 15;
                    acc += a * src2[(size_t)((gg*Lq + l)*Sq + ss)*Dm + koff + tid];
                }
            }
            s_f[tid] = acc;
        }
    }
    __syncthreads();
    for (int c = tid; c < Dm; c += 256) {
        float acc = 0.f;
        #pragma unroll 10
        for (int i = 0; i < 100; ++i)
            acc += s_f[i] * Wf[(k0 + i)*Dm + c];
        part[(size_t)j*Lq*Dm + l*Dm + c] = acc;
    }
}

// ---------------- Kernel F2: combine + relu + out matvec + log_softmax -----------
__global__ __launch_bounds__(256) void fuse2_kernel(
    const float* __restrict__ part, const float* __restrict__ bf,
    const float* __restrict__ Wout, const float* __restrict__ bout,
    float* __restrict__ out)
{
    int l = blockIdx.x, tid = threadIdx.x;
    __shared__ float s_h1[Dm];
    __shared__ float s_logit[7];
    for (int c = tid; c < Dm; c += 256) {
        float acc = bf[c];
        #pragma unroll
        for (int j = 0; j < 9; ++j)
            acc += part[(size_t)j*Lq*Dm + l*Dm + c];
        s_h1[c] = fmaxf(acc, 0.f);
    }
    __syncthreads();
    if (tid < 64) {
        for (int c = 0; c < 7; ++c) {
            float acc = 0.f;
            for (int i = tid; i < Dm; i += 64) acc += s_h1[i]*Wout[i*7+c];
            for (int off = 32; off > 0; off >>= 1) acc += __shfl_down(acc, off);
            if (tid == 0) s_logit[c] = acc + bout[c];
        }
    }
    __syncthreads();
    if (tid == 0) {
        float mx = s_logit[0];
        for (int c = 1; c < 7; ++c) mx = fmaxf(mx, s_logit[c]);
        float Z = 0.f;
        for (int c = 0; c < 7; ++c) Z += expf(s_logit[c]-mx);
        float lz = logf(Z) + mx;
        for (int c = 0; c < 7; ++c) out[l*7+c] = s_logit[c] - lz;
    }
}

extern "C" void kernel_launch(void* const* d_in, const int* in_sizes, int n_in,
                              void* d_out, int out_size, void* d_ws, size_t ws_size,
                              hipStream_t stream)
{
    const float* utt   = (const float*)d_in[0];
    const int* str_src = (const int*)d_in[1];
    const int* str_dst = (const int*)d_in[2];
    const int* str_et  = (const int*)d_in[3];
    const int* csrc    = (const int*)d_in[4];
    const int* cdst    = (const int*)d_in[5];
    const float* cw    = (const float*)d_in[6];
    const float* csen  = (const float*)d_in[7];
    const float* table = (const float*)d_in[8];
    const float* Wb    = (const float*)d_in[9];
    const float* comp  = (const float*)d_in[10];
    const float* Wself = (const float*)d_in[11];
    const float* brg   = (const float*)d_in[12];
    const float* Wq    = (const float*)d_in[13];
    const float* Wk    = (const float*)d_in[14];
    const float* Wv    = (const float*)d_in[15];
    const float* Wo    = (const float*)d_in[16];
    const float* rvec  = (const float*)d_in[17];
    const float* Wf    = (const float*)d_in[18];
    const float* bf    = (const float*)d_in[19];
    const float* Wout  = (const float*)d_in[20];
    const float* bout  = (const float*)d_in[21];

    float* ws   = (float*)d_ws;
    float* P0   = ws;               // 76800
    float* P1   = P0 + 76800;
    float* Q    = P1 + 76800;
    float* Km   = Q  + 76800;
    float* Vm   = Km + 76800;
    float* Hrg  = Vm + 76800;
    float* rel  = Hrg + 76800;
    float* score= rel + 76800;      // 12288 (256*48)
    float* part = score + 12288;    // 691200 (9*256*300)
    float* src2 = part + 691200;    // 3,686,400

    mm6_kernel<<<dim3(64,6), 256, 0, stream>>>(utt, Wb, Wself, brg, Wq, Wk, Wv,
                                               P0, P1, Hrg, Q, Km, Vm);
    rgcn_edge_kernel<<<Eq, 64, 0, stream>>>(str_src, str_dst, str_et, comp, P0, P1, Hrg);
    attn_out_kernel<<<dim3(Lq,2), 256, 0, stream>>>(Q, Km, Vm, Wo, rel);
    concept_kernel<<<3*Lq*Sq, 256, 0, stream>>>(csrc, cdst, cw, csen, table, rel,
                                                rvec, src2, score);
    fuse1_kernel<<<dim3(Lq,9), 256, 0, stream>>>(Hrg, rel, score, src2, Wf, part);
    fuse2_kernel<<<Lq, 256, 0, stream>>>(part, bf, Wout, bout, (float*)d_out);
}